// Round 12
// baseline (209.217 us; speedup 1.0000x reference)
//
#include <hip/hip_runtime.h>
#include <stdint.h>

typedef float f32x4 __attribute__((ext_vector_type(4)));
typedef int   i32x8 __attribute__((ext_vector_type(8)));
typedef long  i64x2 __attribute__((ext_vector_type(2)));
typedef long  i64x4 __attribute__((ext_vector_type(4)));

#define VOCAB 4096
#define DIM   256
#define NROWS 65536             // 32*2048
#define CTILE 32
#define NT (VOCAB/CTILE)        // 128 col-tiles
#define NQUAD (NT/4)            // 32 quad-rounds (4 tiles = 32 KB per round)
#define RPW 64                  // rows per wave: 4 row-slices of 16
#define NRS 4                   // row-slices per wave
#define WPB 4                   // waves per block
#define ROWS_PER_BLOCK (WPB*RPW)        // 256
#define NBLK (NROWS/ROWS_PER_BLOCK)     // 256 blocks = exactly 1 per CU
#define WGRPS (NROWS/RPW)       // 1024 row-waves
#define SSCALE 4096.0f

#if defined(__has_builtin)
#if __has_builtin(__builtin_amdgcn_mfma_scale_f32_16x16x128_f8f6f4)
#define HAVE_MXFMA 1
#endif
#endif

// Pack 8 consecutive-k floats -> 8 fp8 bytes. A and B both use THIS helper,
// so any byte-permutation cancels in the MFMA contraction.
static __device__ __forceinline__ long pk8(float4 a, float4 b) {
    int lo = __builtin_amdgcn_cvt_pk_fp8_f32(a.x, a.y, 0, false);
    lo     = __builtin_amdgcn_cvt_pk_fp8_f32(a.z, a.w, lo, true);
    int hi = __builtin_amdgcn_cvt_pk_fp8_f32(b.x, b.y, 0, false);
    hi     = __builtin_amdgcn_cvt_pk_fp8_f32(b.z, b.w, hi, true);
    return (long)(unsigned)lo | ((long)hi << 32);
}
static __device__ __forceinline__ float4 sc4(float4 v, float s) {
    float4 r; r.x = s*v.x; r.y = s*v.y; r.z = s*v.z; r.w = s*v.w; return r;
}

// Prep: eimg = fp8(-2*S*emb) in per-lane fragment order:
// tile ct (32 cols, 8 KB): region r = sub*2+kb (2 KB), halves h (1 KB):
// byte [r*2048 + h*1024 + lane*16 + j] <-> col = sub*16 + (lane&15),
// k = kb*128 + (lane>>4)*32 + h*16 + j.   e2s[v] = sum(emb[v]^2) (loss only).
// NOTE: every 1 KB chunk is lane*16-contiguous == global_load_lds write order.
__global__ void vq_prep(const float* __restrict__ emb, uint8_t* __restrict__ eimg,
                        float* __restrict__ e2s) {
    const int t = threadIdx.x, tile = blockIdx.x;
    const int C0 = tile * CTILE;
    const int l = t & 63, q = l >> 4, n = l & 15;
    const int r = t >> 6;               // sub*2 + kb
    const int sub = r >> 1, kb = r & 1;
    const float s = -2.0f * SSCALE;
    uint8_t* tb = eimg + (size_t)tile * 8192 + r * 2048 + l * 16;
    const float* erow = emb + (size_t)(C0 + sub*16 + n) * DIM + kb*128 + q*32;
    #pragma unroll
    for (int h = 0; h < 2; ++h) {
        const float4* p = (const float4*)(erow + h*16);
        i64x2 L;
        L.x = pk8(sc4(p[0], s), sc4(p[1], s));
        L.y = pk8(sc4(p[2], s), sc4(p[3], s));
        *(i64x2*)(tb + h*1024) = L;
    }
    const int c = t >> 3, seg = t & 7;
    const float4* er = (const float4*)(emb + (size_t)(C0 + c) * DIM + seg*32);
    float ss = 0.f;
    #pragma unroll
    for (int i = 0; i < 8; ++i) {
        float4 v = er[i];
        ss += v.x*v.x + v.y*v.y + v.z*v.z + v.w*v.w;
    }
    ss += __shfl_xor(ss, 1); ss += __shfl_xor(ss, 2); ss += __shfl_xor(ss, 4);
    if (seg == 0) e2s[C0 + c] = ss;
}

// FUSED K1 (r12): 1 block per CU, 4 waves, RPW=64 (4 row-slices): each LDS
// B-byte now feeds 2x the MFMAs of r11 — LDS pipe (r11's dominant consumer,
// ~55% of cycles: 8192 ds_read_b128/CU) halves to ~4096 reads/CU. Quad-tile
// rounds (32 KB, 32 barriers) halve round-overhead count vs r11's 64.
// Counted vmcnt(8) + raw s_barrier keeps quad t+2's 8 DMAs in flight across
// the barrier (r10/r11-verified). 1 wave/SIMD: MFMA pipe fed by ILP (4
// independent acc chains per tile).
// REGISTER HISTORY: (64,4)=128-cap spilled 186 MB (r4), (64,3)=168-cap
// spilled 107 MB (r5). Here (256,1) = 512-reg budget and the VGPR pool still
// fits the 4 resident waves -> spill-free BY CONSTRUCTION, not estimate.
__global__ __launch_bounds__(256, 1) void vq_argmin(
        const float* __restrict__ x, const uint8_t* __restrict__ eimg,
        const float* __restrict__ e2s, const float* __restrict__ emb,
        float* __restrict__ out, float* __restrict__ parts) {
    __shared__ __align__(16) uint8_t bsm[3][32768];
    __shared__ int idx_lds[ROWS_PER_BLOCK];
    const int tid  = threadIdx.x;
    const int lane = tid & 63;
    const int wv   = tid >> 6;
    const int quad = lane >> 4;
    const int l16  = lane & 15;
    const int rowblock = blockIdx.x * ROWS_PER_BLOCK;   // 0..255 * 256
    const int waverow  = rowblock + wv * RPW;
    const int wgrp     = blockIdx.x * WPB + wv;         // 0..1023
    const int pstart   = blockIdx.x & (NQUAD - 1);      // stagger the sweep

    // Stage quad p (32 KB = tiles 4p..4p+3) into bsm[buf]: 32 chunks of 1 KB,
    // 8 per wave, each one global_load_lds (64 lanes x 16 B, linear dst).
    auto stage = [&](int buf, int p) {
        const uint8_t* src = eimg + ((size_t)p << 15) + (size_t)(wv * 8) * 1024 + (size_t)lane * 16;
        uint8_t* dst = &bsm[buf][(wv * 8) * 1024];
        #pragma unroll
        for (int c = 0; c < 8; ++c)
            __builtin_amdgcn_global_load_lds(
                (const __attribute__((address_space(1))) uint32_t*)(src + c * 1024),
                (__attribute__((address_space(3))) uint32_t*)(dst + c * 1024), 16, 0, 0);
    };

    // Prologue: stage quads 0 and 1; their latency hides under the A-prep.
    stage(0, pstart);
    stage(1, (pstart + 1) & (NQUAD - 1));

    // ---- A fragments: fp8(x), 64 rows/wave = 64 VGPRs (pairwise-consume
    // load batches, r3/r6-proven at RPW=64). ----
    i64x4 A[NRS][2];
    float ss = 0.f;
    #pragma unroll
    for (int rs = 0; rs < NRS; ++rs) {
        const float* xrow = x + (size_t)(waverow + rs*16 + l16) * DIM + quad*32;
        #pragma unroll
        for (int kb = 0; kb < 2; ++kb) {
            const float4* p = (const float4*)(xrow + kb*128);
            i64x4 a;
            #pragma unroll
            for (int j = 0; j < 4; ++j) {
                float4 u0 = p[2*j], u1 = p[2*j+1];
                ss += u0.x*u0.x + u0.y*u0.y + u0.z*u0.z + u0.w*u0.w
                    + u1.x*u1.x + u1.y*u1.y + u1.z*u1.z + u1.w*u1.w;
                a[j] = pk8(u0, u1);
            }
            A[rs][kb] = a;
        }
    }
    // ss: full-wave sum of x^2 over this wave's 64 rows -> lane 0.
    #pragma unroll
    for (int off = 32; off; off >>= 1) ss += __shfl_down(ss, off);

    float rmin[NRS][4];
    #pragma unroll
    for (int rs = 0; rs < NRS; ++rs)
        #pragma unroll
        for (int r = 0; r < 4; ++r) rmin[rs][r] = 3.402823466e+38f;

    union BU { i32x8 v; i64x4 q; struct { int4 lo, hi; } s; };

    // Full MFMA + pack/min work for one 32-col tile; `half` in 0..3 selects
    // the 8 KB sub-buffer of the 32 KB quad, ctv is the GLOBAL tile index.
    auto computeT = [&](int buf, int half, int ctv) {
        const uint8_t* base = &bsm[buf][half * 8192] + (size_t)lane * 16;
        BU b[2][2];
        #pragma unroll
        for (int sub = 0; sub < 2; ++sub)
            #pragma unroll
            for (int kb = 0; kb < 2; ++kb) {
                const uint8_t* pB = base + (sub*2 + kb) * 2048;
                b[sub][kb].s.lo = *(const int4*)pB;
                b[sub][kb].s.hi = *(const int4*)(pB + 1024);
            }
        const int colbase = ctv * CTILE;
        #pragma unroll
        for (int sub = 0; sub < 2; ++sub) {
            f32x4 acc[NRS];
            #pragma unroll
            for (int rs = 0; rs < NRS; ++rs) acc[rs] = (f32x4){0.f,0.f,0.f,0.f};
            __builtin_amdgcn_s_setprio(1);
            #pragma unroll
            for (int kb = 0; kb < 2; ++kb) {
#ifdef HAVE_MXFMA
                #pragma unroll
                for (int rs = 0; rs < NRS; ++rs)
                    acc[rs] = __builtin_amdgcn_mfma_scale_f32_16x16x128_f8f6f4(
                        __builtin_bit_cast(i32x8, A[rs][kb]), b[sub][kb].v, acc[rs],
                        0, 0, 0, 0x7F7F7F7F, 0, 0x7F7F7F7F);
#else
                #pragma unroll
                for (int rs = 0; rs < NRS; ++rs) {
                    acc[rs] = __builtin_amdgcn_mfma_f32_16x16x32_fp8_fp8(A[rs][kb].x, b[sub][kb].q.x, acc[rs], 0, 0, 0);
                    acc[rs] = __builtin_amdgcn_mfma_f32_16x16x32_fp8_fp8(A[rs][kb].y, b[sub][kb].q.y, acc[rs], 0, 0, 0);
                    acc[rs] = __builtin_amdgcn_mfma_f32_16x16x32_fp8_fp8(A[rs][kb].z, b[sub][kb].q.z, acc[rs], 0, 0, 0);
                    acc[rs] = __builtin_amdgcn_mfma_f32_16x16x32_fp8_fp8(A[rs][kb].w, b[sub][kb].q.w, acc[rs], 0, 0, 0);
                }
#endif
            }
            __builtin_amdgcn_s_setprio(0);
            const unsigned colv = (unsigned)(colbase + sub*16 + l16);
            // C layout: row = quad*4 + r, col = l16. idx packed in low 12 mantissa
            // bits -> one v_and_or + one v_min_f32 carries (score, idx).
            #pragma unroll
            for (int rs = 0; rs < NRS; ++rs)
                #pragma unroll
                for (int r = 0; r < 4; ++r) {
                    unsigned pk = (__float_as_uint(acc[rs][r]) & 0xFFFFF000u) | colv;
                    rmin[rs][r] = fminf(rmin[rs][r], __uint_as_float(pk));
                }
        }
    };

    __syncthreads();            // prologue: quads 0,1 staged (full drain, once)

    #pragma unroll 1
    for (int t = 0; t < NQUAD; ++t) {
        if (t + 2 < NQUAD) stage((t + 2) % 3, (pstart + t + 2) & (NQUAD - 1));
        const int p = (pstart + t) & (NQUAD - 1);
        computeT(t % 3, 0, 4 * p);
        computeT(t % 3, 1, 4 * p + 1);
        computeT(t % 3, 2, 4 * p + 2);
        computeT(t % 3, 3, 4 * p + 3);
        // Counted wait: quad t+1's DMAs (issued at t-1) must have landed;
        // quad t+2's 8 loads stay in flight across the raw barrier.
        if (t + 2 < NQUAD) {
            asm volatile("s_waitcnt vmcnt(8)" ::: "memory");
        } else {
            asm volatile("s_waitcnt vmcnt(0)" ::: "memory");
        }
        __builtin_amdgcn_s_barrier();
    }

    // ---- Winners: 16-lane reduce, record idx + loss contribution ----
    float lsum = 0.f;
    #pragma unroll
    for (int rs = 0; rs < NRS; ++rs) {
        #pragma unroll
        for (int r = 0; r < 4; ++r) {
            float v = rmin[rs][r];
            v = fminf(v, __shfl_xor(v, 8));
            v = fminf(v, __shfl_xor(v, 4));
            v = fminf(v, __shfl_xor(v, 2));
            v = fminf(v, __shfl_xor(v, 1));
            if (l16 == 0) {
                unsigned u = __float_as_uint(v);
                int idx = (int)(u & 0xFFFu);
                idx_lds[wv*RPW + rs*16 + quad*4 + r] = idx;
                lsum += __uint_as_float(u & 0xFFFFF000u) * (1.0f / SSCALE) + e2s[idx];
            }
        }
    }
    // lsum lives in lanes 0,16,32,48 -> lane 0; combine with ss.
    lsum += __shfl_down(lsum, 32);
    lsum += __shfl_down(lsum, 16);
    if (lane == 0) parts[wgrp] = ss + lsum;

    __syncthreads();                    // idx_lds visible to all waves

    // ---- Gather emb[idx] -> out: 256 rows x 64 float4, 64 per thread.
    // Uniform idx per row -> coalesced 1 KB read from L2-resident emb,
    // coalesced 1 KB write to out.
    #pragma unroll 4
    for (int it = 0; it < 64; ++it) {
        int fi  = it * 256 + tid;
        int row = fi >> 6;
        int c4  = fi & 63;
        float4 q = ((const float4*)(emb + (size_t)idx_lds[row] * DIM))[c4];
        ((float4*)(out + (size_t)(rowblock + row) * DIM))[c4] = q;
    }
}

// K3: loss = 1.25/Nel * sum parts[1024]
__global__ void vq_loss(const float* __restrict__ parts,
                        float* __restrict__ loss_slot) {
    __shared__ float wsum[4];
    const int tid = threadIdx.x;
    float s = 0.f;
    #pragma unroll
    for (int i = 0; i < WGRPS/256; ++i) s += parts[i * 256 + tid];
    #pragma unroll
    for (int off = 32; off; off >>= 1) s += __shfl_down(s, off);
    if ((tid & 63) == 0) wsum[tid >> 6] = s;
    __syncthreads();
    if (tid == 0)
        loss_slot[0] = (wsum[0] + wsum[1] + wsum[2] + wsum[3]) * (1.25f / 16777216.f);
}

extern "C" void kernel_launch(void* const* d_in, const int* in_sizes, int n_in,
                              void* d_out, int out_size, void* d_ws, size_t ws_size,
                              hipStream_t stream) {
    const float* x   = (const float*)d_in[0];   // [32,2048,256]
    const float* emb = (const float*)d_in[1];   // [4096,256]
    float* out = (float*)d_out;                 // 16777216 quantised_st + 1 loss

    uint8_t* eimg = (uint8_t*)d_ws;                                    // 1 MB
    float* e2s    = (float*)((char*)d_ws + (size_t)VOCAB*DIM);         // 16 KB
    float* parts  = (float*)((char*)e2s + VOCAB*4);                    // 4 KB
    float* loss_slot = out + (size_t)NROWS * DIM;

    vq_prep<<<VOCAB/CTILE, 256, 0, stream>>>(emb, eimg, e2s);
    vq_argmin<<<NBLK, 64*WPB, 0, stream>>>(x, eimg, e2s, emb, out, parts);
    vq_loss<<<1, 256, 0, stream>>>(parts, loss_slot);
}